// Round 2
// baseline (14025.665 us; speedup 1.0000x reference)
//
#include <hip/hip_runtime.h>

#define NB 64
#define NC 32
#define NH 16
#define NW 16
#define NE 4096
#define NTOT (NB*NC*NH*NW)   // 524288
#define IDXW 341             // 1+4+16+64+256
#define GRID 256
#define TPB 1024

__device__ __forceinline__ double cubicw(double x) {
  const double A = -0.75;
  x = fabs(x);
  if (x <= 1.0) return ((A + 2.0) * x - (A + 3.0)) * x * x + 1.0;
  if (x < 2.0)  return A * (((x - 5.0) * x + 8.0) * x - 4.0);
  return 0.0;
}

// 4-block group barrier: publishes are sc0sc1 (agent-scope atomics, coherent at
// IF$), __syncthreads drains vmcnt per thread, flag add+poll is relaxed agent.
// No __threadfence => no buffer_wbl2 / buffer_inv => L2 stays warm.
__device__ __forceinline__ void groupbar(unsigned* fl) {
  __syncthreads();    // all threads' coherent stores acked (vmcnt0 before barrier)
  if (threadIdx.x == 0) {
    __hip_atomic_fetch_add(fl, 1u, __ATOMIC_RELAXED, __HIP_MEMORY_SCOPE_AGENT);
    while (__hip_atomic_load(fl, __ATOMIC_RELAXED, __HIP_MEMORY_SCOPE_AGENT) < 4u)
      __builtin_amdgcn_s_sleep(2);
  }
  __syncthreads();
}

__global__ __launch_bounds__(TPB, 4) void k_fused(
    const float* __restrict__ z, const float* __restrict__ emb,
    const float* __restrict__ phi_w, const float* __restrict__ phi_b,
    double* __restrict__ rv_pub, double* __restrict__ cand_d,
    int* __restrict__ cand_i, unsigned* __restrict__ flags,
    double* __restrict__ loss_d, unsigned* __restrict__ cnt,
    float* __restrict__ out_zhat, float* __restrict__ out_loss,
    float* __restrict__ out_idx)
{
  __shared__ double lds[8192];                 // 64 KB exactly
  double* zres = lds;                          // [8][256] f64   bytes [0,16384)
  char*  qreg  = (char*)lds + 16384;           // 32 KB multi-use [16384,49152)
  char*  ttreg = (char*)lds + 49152;           // 16 KB multi-use [49152,65536)

  const int tid = threadIdx.x;
  const int b = blockIdx.x >> 2, jq = blockIdx.x & 3;
  const int co0 = jq * 8, e_base = jq << 10;

  // idempotent CAS-init of poisoned (0xAA) sync cells by every block
  if (tid < 16) atomicCAS(&flags[(b << 4) + tid], 0xAAAAAAAAu, 0u);
  if (tid == 0) {
    atomicCAS((unsigned long long*)loss_d, 0xAAAAAAAAAAAAAAAAull, 0ull);
    atomicCAS(cnt, 0xAAAAAAAAu, 0u);
  }

  // per-thread codebook row (code e_base+tid) in registers + ||e||^2
  float eq[32]; double esq = 0.0;
  {
    const float4* ep = (const float4*)(emb + (e_base + tid) * NC);
    #pragma unroll
    for (int g = 0; g < 8; g++) {
      float4 v = ep[g];
      eq[4*g+0] = v.x; eq[4*g+1] = v.y; eq[4*g+2] = v.z; eq[4*g+3] = v.w;
    }
    #pragma unroll
    for (int k = 0; k < NC; k++) esq += (double)eq[k] * (double)eq[k];
  }
  // z_res own-channel slice -> LDS (f64)
  #pragma unroll
  for (int t = 0; t < 2; t++) {
    int i = t * TPB + tid;                     // i = cc*256 + pix
    zres[i] = (double)z[((b * NC + co0) << 8) + i];
  }
  __syncthreads();

  double bloss = 0.0;
  const int phs[5]  = {1, 2, 4, 8, 16};
  // ticks = np.linspace(1/12, 11/12, 4) f64: si=2 tie breaks to pi=2
  const int pis[5]  = {0, 1, 2, 2, 3};
  const int offs[5] = {0, 1, 5, 21, 85};

  for (int si = 0; si < 5; si++) {
    const int ph = phs[si], f = NH / ph, ph2 = ph * ph;

    // ---------- pool own 8 channels (LDS) -> publish rv (coherent) ----------
    if (si == 4) {
      #pragma unroll
      for (int t = 0; t < 2; t++) {
        int i = t * TPB + tid;
        int cc = i >> 8, pix = i & 255;        // row n = y*16+x = pix
        __hip_atomic_store(&rv_pub[((b << 8) + pix) * NC + co0 + cc], zres[i],
                           __ATOMIC_RELAXED, __HIP_MEMORY_SCOPE_AGENT);
      }
    } else {
      double* pp = (double*)qreg;              // [work] partials
      int P = (f >= 8) ? 8 : f;                // si0:8 si1:8 si2:4 si3:2
      int items = 8 * ph2, work = items * P, dpp = f / P;
      if (tid < work) {
        int it = tid / P, part = tid - it * P;
        int cc = it / ph2, rem = it - cc * ph2;
        int y = rem / ph, x = rem - y * ph;
        const double* basep = zres + cc * 256 + (y * f) * 16 + x * f;
        double s = 0.0;
        for (int dy = part * dpp; dy < part * dpp + dpp; dy++) {
          const double* rp = basep + dy * 16;
          for (int dx = 0; dx < f; dx++) s += rp[dx];
        }
        pp[tid] = s;
      }
      __syncthreads();
      if (tid < items) {
        double s = 0.0;
        for (int p2 = 0; p2 < P; p2++) s += pp[tid * P + p2];
        int cc = tid / ph2, rem = tid - cc * ph2;
        __hip_atomic_store(&rv_pub[((b << 8) + rem) * NC + co0 + cc],
                           s / (double)(f * f),
                           __ATOMIC_RELAXED, __HIP_MEMORY_SCOPE_AGENT);
      }
    }
    groupbar(&flags[(b << 4) + si * 2]);

    // ---------- argmin: scan own 1024-code quarter, 16 rows/chunk ----------
    {
      double* rvt = (double*)qreg;             // [32][16] staged pooled rows
      double* xw  = rvt + 512;                 // [16 waves][16 rows] packed
      const int lane = tid & 63, wv_ = tid >> 6;
      int nch = (ph2 + 15) >> 4;               // 1,1,1,4,16 (rows padded to 16)
      for (int chn = 0; chn < nch; chn++) {
        int row0 = chn << 4;
        if (tid < 512) {                       // stage rvt[k][r]
          int k = tid >> 4, r = tid & 15;
          rvt[tid] = __hip_atomic_load(&rv_pub[((b << 8) + row0 + r) * NC + k],
                                       __ATOMIC_RELAXED, __HIP_MEMORY_SCOPE_AGENT);
        }
        __syncthreads();
        double acc[16];
        #pragma unroll
        for (int r = 0; r < 16; r++) acc[r] = 0.0;
        #pragma unroll
        for (int k = 0; k < NC; k++) {
          double ek = (double)eq[k];
          #pragma unroll
          for (int r = 0; r < 16; r++) acc[r] = fma(rvt[k * 16 + r], ek, acc[r]);
        }
        // d = ||e||^2 - 2 r.e ; pack 10-bit in-quarter id into low mantissa
        // bits (2^-42 relative perturbation << inter-code gaps) -> pure fmin
        // butterfly; unique ids => unique winner.
        #pragma unroll
        for (int r = 0; r < 16; r++) {
          double d = esq - 2.0 * acc[r];
          unsigned long long du =
              (__double_as_longlong(d) & ~1023ull) | (unsigned long long)tid;
          double dp = __longlong_as_double(du);
          #pragma unroll
          for (int off = 32; off >= 1; off >>= 1)
            dp = fmin(dp, __shfl_xor(dp, off, 64));
          if (lane == 0) xw[wv_ * 16 + r] = dp;
        }
        __syncthreads();
        if (tid < 16) {                        // cross-wave + publish candidate
          double m = xw[tid];
          #pragma unroll
          for (int w2 = 1; w2 < 16; w2++) m = fmin(m, xw[w2 * 16 + tid]);
          int inq = (int)(__double_as_longlong(m) & 1023ull);
          int gr = (b << 2) + jq;
          __hip_atomic_store(&cand_d[(gr << 8) + row0 + tid], m,
                             __ATOMIC_RELAXED, __HIP_MEMORY_SCOPE_AGENT);
          __hip_atomic_store(&cand_i[(gr << 8) + row0 + tid], e_base + inq,
                             __ATOMIC_RELAXED, __HIP_MEMORY_SCOPE_AGENT);
        }
        __syncthreads();
      }
    }
    groupbar(&flags[(b << 4) + si * 2 + 1]);

    // ---------- combine quarters (redundant per block) ----------
    unsigned short* fidx = (unsigned short*)(ttreg + 8192);  // [<=256]
    if (tid < ph2) {
      double bd = 0.0; int bi = 0;
      #pragma unroll
      for (int q4 = 0; q4 < 4; q4++) {         // ordered: tie -> lower idx
        double d = __hip_atomic_load(&cand_d[((b << 2) + q4) * 256 + tid],
                                     __ATOMIC_RELAXED, __HIP_MEMORY_SCOPE_AGENT);
        int ii = __hip_atomic_load(&cand_i[((b << 2) + q4) * 256 + tid],
                                   __ATOMIC_RELAXED, __HIP_MEMORY_SCOPE_AGENT);
        if (q4 == 0 || d < bd) { bd = d; bi = ii; }
      }
      fidx[tid] = (unsigned short)bi;
      if (jq == 0) out_idx[b * IDXW + offs[si] + tid] = (float)bi;
    }
    __syncthreads();

    // ---------- upsample: full 32-ch q in LDS (redundant x4, cheap) ----------
    float* simg = (float*)qreg;                // [32][256] f32
    if (si == 4) {
      for (int i = tid; i < 32 * 256; i += TPB)
        simg[i] = emb[(int)fidx[i & 255] * NC + (i >> 8)];
    } else {
      double* wtab = (double*)(ttreg + 8704);  // [16][4] cubic weights
      int* itab = (int*)(ttreg + 9216);        // [16] i0
      double scale = (double)ph / 16.0;
      if (tid < 64) {
        int oy = tid >> 2, kk = tid & 3;
        double src = ((double)oy + 0.5) * scale - 0.5;
        double fi = floor(src);
        if (kk == 0) itab[oy] = (int)fi;
        wtab[tid] = cubicw(src - fi - (double)(kk - 1));
      }
      __syncthreads();
      int CH = (si == 3) ? 16 : 32, nhalf = (si == 3) ? 2 : 1;
      float* qs = (float*)(qreg + 28672);      // <=4 KB gather buf (q ch28-31)
      float* tt = (float*)ttreg;               // <=8 KB H-pass intermediate
      for (int half = 0; half < nhalf; half++) {
        int c0 = half * CH;
        for (int i = tid; i < CH * ph2; i += TPB) {
          int cc = i / ph2, rem = i - cc * ph2;
          qs[i] = emb[(int)fidx[rem] * NC + c0 + cc];
        }
        __syncthreads();
        for (int i = tid; i < CH * 16 * ph; i += TPB) {   // H pass
          int x = i % ph, oy = (i / ph) & 15, cc = i / (16 * ph);
          int i0 = itab[oy];
          double s = 0.0;
          #pragma unroll
          for (int k = 0; k < 4; k++) {
            int iy = min(max(i0 + k - 1, 0), ph - 1);
            s += wtab[oy * 4 + k] * (double)qs[(cc * ph + iy) * ph + x];
          }
          tt[i] = (float)s;
        }
        __syncthreads();
        for (int i = tid; i < CH * 256; i += TPB) {       // W pass
          int ox = i & 15, oy = (i >> 4) & 15, cc = i >> 8;
          int i0 = itab[ox];
          double s = 0.0;
          #pragma unroll
          for (int k = 0; k < 4; k++) {
            int ix = min(max(i0 + k - 1, 0), ph - 1);
            s += wtab[ox * 4 + k] * (double)tt[(cc * 16 + oy) * ph + ix];
          }
          simg[(c0 + cc) * 256 + oy * 16 + ox] = (float)s;
        }
        __syncthreads();
      }
    }
    __syncthreads();

    // ---------- phi: 0.5*x + 0.5*(conv3x3(x)+b); own channels; LDS z_res ----
    {
      float* lw = (float*)ttreg;               // [8][32][9] weight slice 9216 B
      const float* wsrc = phi_w + (pis[si] * NC + co0) * NC * 9;
      for (int i = tid; i < 8 * NC * 9; i += TPB) lw[i] = wsrc[i];
      __syncthreads();
      int pix = tid & 255, sub = tid >> 8;     // 4 subs x 2 co = 8 co
      int x = pix & 15, y = pix >> 4;
      double a0 = 0.0, a1 = 0.0;
      for (int ci = 0; ci < NC; ci++) {
        double wv[9];
        #pragma unroll
        for (int ky = 0; ky < 3; ky++) {
          int yy = y + ky - 1;
          #pragma unroll
          for (int kx = 0; kx < 3; kx++) {
            int xx = x + kx - 1;
            wv[ky * 3 + kx] = (yy >= 0 && yy < NH && xx >= 0 && xx < NW)
                              ? (double)simg[(ci << 8) + yy * 16 + xx] : 0.0;
          }
        }
        const float* wp0 = lw + ((sub * 2 + 0) * NC + ci) * 9;  // wave-uniform
        const float* wp1 = lw + ((sub * 2 + 1) * NC + ci) * 9;
        #pragma unroll
        for (int k = 0; k < 9; k++) a0 += wv[k] * (double)wp0[k];
        #pragma unroll
        for (int k = 0; k < 9; k++) a1 += wv[k] * (double)wp1[k];
      }
      double lsum = 0.0;
      #pragma unroll
      for (int jj = 0; jj < 2; jj++) {
        int col = sub * 2 + jj;
        double aj = jj ? a1 : a0;
        double val = (double)simg[((co0 + col) << 8) + pix] * 0.5
                   + (aj + (double)phi_b[pis[si] * NC + co0 + col]) * 0.5;
        int li = (col << 8) + pix;
        double zr = zres[li] - val;
        zres[li] = zr;
        if (si == 4) {
          int gi = ((b * NC + co0 + col) << 8) + pix;
          out_zhat[gi] = (float)((double)z[gi] - zr);
        }
        lsum += zr * zr;                       // z_hat - z == -z_res
      }
      __syncthreads();                         // simg consumed
      double* red = (double*)qreg;
      red[tid] = lsum; __syncthreads();
      for (int s = 512; s > 0; s >>= 1) {
        if (tid < s) red[tid] += red[tid + s];
        __syncthreads();
      }
      if (tid == 0) bloss += red[0];
      __syncthreads();
    }
  }

  // ---------- global loss: one f64 atomic per block; last arriver writes ----
  if (tid == 0) {
    double old = unsafeAtomicAdd(loss_d, bloss); (void)old;
    asm volatile("s_waitcnt vmcnt(0)" ::: "memory");
    unsigned n = __hip_atomic_fetch_add(cnt, 1u, __ATOMIC_RELAXED,
                                        __HIP_MEMORY_SCOPE_AGENT);
    if (n == GRID - 1u) {
      double tot = __hip_atomic_load(loss_d, __ATOMIC_RELAXED,
                                     __HIP_MEMORY_SCOPE_AGENT);
      *out_loss = (float)(tot * (1.25 / (5.0 * (double)NTOT)));
    }
  }
}

extern "C" void kernel_launch(void* const* d_in, const int* in_sizes, int n_in,
                              void* d_out, int out_size, void* d_ws, size_t ws_size,
                              hipStream_t stream) {
  const float* z     = (const float*)d_in[0];   // [64,32,16,16]
  const float* emb   = (const float*)d_in[1];   // [4096,32]
  const float* phi_w = (const float*)d_in[2];   // [4,32,32,3,3]
  const float* phi_b = (const float*)d_in[3];   // [4,32]

  float* out      = (float*)d_out;
  float* out_zhat = out;
  float* out_loss = out + NTOT;
  float* out_idx  = out + NTOT + 1;             // [64,341] as floats

  double* ws      = (double*)d_ws;
  double* rv_pub  = ws;                          // 64*256*32 f64 = 4 MB
  double* cand_d  = rv_pub + 64 * 256 * NC;      // 64*4*256 f64
  int*    cand_i  = (int*)(cand_d + 64 * 4 * 256);      // 64*4*256 i32
  double* loss_d  = (double*)(cand_i + 64 * 4 * 256);   // 1 f64 (8-aligned)
  unsigned* cnt   = (unsigned*)(loss_d + 1);     // 1 u32
  unsigned* flags = cnt + 1;                     // 64*16 u32 one-shot

  k_fused<<<GRID, TPB, 0, stream>>>(z, emb, phi_w, phi_b,
                                    rv_pub, cand_d, cand_i, flags, loss_d, cnt,
                                    out_zhat, out_loss, out_idx);
}

// Round 3
// 603.276 us; speedup vs baseline: 23.2492x; 23.2492x over previous
//
#include <hip/hip_runtime.h>

#define NB 64
#define NC 32
#define NH 16
#define NW 16
#define NE 4096
#define NTOT (NB*NC*NH*NW)   // 524288
#define IDXW 341             // 1+4+16+64+256
#define GRID 256
#define TPB 1024

__device__ __forceinline__ double cubicw(double x) {
  const double A = -0.75;
  x = fabs(x);
  if (x <= 1.0) return ((A + 2.0) * x - (A + 3.0)) * x * x + 1.0;
  if (x < 2.0)  return A * (((x - 5.0) * x + 8.0) * x - 4.0);
  return 0.0;
}

__device__ __forceinline__ unsigned aload(unsigned* p) {
  return __hip_atomic_load(p, __ATOMIC_RELAXED, __HIP_MEMORY_SCOPE_AGENT);
}

// 4-party group barrier, fence-free: publishes use sc0sc1 stores (coherent
// point), __syncthreads drains each thread's vmcnt BEFORE the arrive-add, and
// the trailing __syncthreads is a compiler memory barrier (no hoisting of the
// post-barrier sc1 loads). Proven in R2 (passed); R2's perf bug was a VGPR
// spill, not this protocol.
__device__ __forceinline__ void groupbar(unsigned* fl) {
  __syncthreads();
  if (threadIdx.x == 0) {
    __hip_atomic_fetch_add(fl, 1u, __ATOMIC_RELAXED, __HIP_MEMORY_SCOPE_AGENT);
    while (aload(fl) < 4u) __builtin_amdgcn_s_sleep(4);
  }
  __syncthreads();
}

__global__ __launch_bounds__(TPB, 4) void k_fused(
    const float* __restrict__ z, const float* __restrict__ emb,
    const float* __restrict__ phi_w, const float* __restrict__ phi_b,
    double* __restrict__ rv_pub, double* __restrict__ emb_sq,
    double* __restrict__ loss_d, float* __restrict__ emb_t,
    int* __restrict__ win, unsigned* __restrict__ cnt,
    unsigned* __restrict__ gbar, unsigned* __restrict__ flags,
    float* __restrict__ out_zhat, float* __restrict__ out_loss,
    float* __restrict__ out_idx)
{
  __shared__ double lds[8192];                 // 64 KB
  double* zres = lds;                          // [8][256] f64, persistent
  char* qreg   = (char*)lds + 16384;           // 32 KB multi-use
  char* ttreg  = (char*)lds + 49152;           // 16 KB multi-use

  const int tid = threadIdx.x;
  const int b = blockIdx.x >> 2, jq = blockIdx.x & 3;
  const int co0 = jq * 8;

  // idempotent CAS-init of poisoned (0xAA) sync cells
  if (tid < 16) atomicCAS(&flags[(b << 4) + tid], 0xAAAAAAAAu, 0u);
  if (tid == 0) {
    atomicCAS((unsigned long long*)loss_d, 0xAAAAAAAAAAAAAAAAull, 0ull);
    atomicCAS(cnt, 0xAAAAAAAAu, 0u);
    atomicCAS(gbar, 0xAAAAAAAAu, 0u);
  }

  // ---------- setup: zres <- z slice; build emb_t (transpose) + emb_sq ------
  #pragma unroll
  for (int t = 0; t < 2; t++) {
    int i = t * TPB + tid;
    zres[i] = (double)z[((b * NC + co0) << 8) + i];
  }
  {
    int c0 = blockIdx.x * 16;                  // 16 codes per block
    if (tid < 512) {
      int cl = tid >> 5, k = tid & 31;
      emb_t[k * NE + c0 + cl] = emb[(c0 + cl) * NC + k];   // read coalesced
    }
    if (tid < 16) {                            // emb_sq, R1's summation order
      const float* er = emb + (c0 + tid) * NC;
      double s = 0.0;
      #pragma unroll
      for (int j = 0; j < 8; j++)
        s += (double)er[4*j]*er[4*j] + (double)er[4*j+1]*er[4*j+1]
           + (double)er[4*j+2]*er[4*j+2] + (double)er[4*j+3]*er[4*j+3];
      emb_sq[c0 + tid] = s;
    }
  }
  // one-time FENCED tree barrier: publishes emb_t/emb_sq (normal stores) for
  // L2-cached reads everywhere after. Only threadfence pair in the kernel.
  __syncthreads();
  if (tid == 0) {
    __threadfence();                           // release (wb L2)
    __hip_atomic_fetch_add(&flags[(b << 4) + 15], 1u, __ATOMIC_RELAXED,
                           __HIP_MEMORY_SCOPE_AGENT);
    if (jq == 0) {
      while (aload(&flags[(b << 4) + 15]) < 4u) __builtin_amdgcn_s_sleep(2);
      __hip_atomic_fetch_add(gbar, 1u, __ATOMIC_RELAXED,
                             __HIP_MEMORY_SCOPE_AGENT);
      while (aload(gbar) < 64u) __builtin_amdgcn_s_sleep(8);
      __hip_atomic_store(&flags[(b << 4) + 14], 1u, __ATOMIC_RELAXED,
                         __HIP_MEMORY_SCOPE_AGENT);
    } else {
      while (aload(&flags[(b << 4) + 14]) < 1u) __builtin_amdgcn_s_sleep(4);
    }
    __threadfence();                           // acquire (inv L2)
  }
  __syncthreads();

  double bloss = 0.0;
  const int phs[5]  = {1, 2, 4, 8, 16};
  // ticks = np.linspace(1/12, 11/12, 4) f64: si=2 tie breaks to pi=2
  const int pis[5]  = {0, 1, 2, 2, 3};
  const int offs[5] = {0, 1, 5, 21, 85};

  for (int si = 0; si < 5; si++) {
    const int ph = phs[si], f = NH / ph, ph2 = ph * ph;

    // ---------- pool own 8 channels (LDS zres) -> publish rv_pub[b][n][c] ---
    if (si == 4) {
      #pragma unroll
      for (int t = 0; t < 2; t++) {
        int i = t * TPB + tid;
        int pix = i >> 3, cc = i & 7;          // 64B-contig runs
        __hip_atomic_store(&rv_pub[((b << 8) + pix) * NC + co0 + cc],
                           zres[cc * 256 + pix],
                           __ATOMIC_RELAXED, __HIP_MEMORY_SCOPE_AGENT);
      }
    } else {
      double* pp = (double*)qreg;
      const int P = (f >= 8) ? 8 : f;          // si0:8 si1:8 si2:4 si3:2
      const int items = 8 * ph2, work = items * P, dpp = f / P;
      if (tid < work) {
        int it = tid / P, part = tid - it * P;
        int cc = it & 7, rem = it >> 3;        // rem-major for coalesced pub
        int y = rem / ph, x = rem - y * ph;
        const double* basep = zres + cc * 256 + (y * f) * 16 + x * f;
        double s = 0.0;
        for (int dy = part * dpp; dy < part * dpp + dpp; dy++) {
          const double* rp = basep + dy * 16;
          #pragma unroll 4
          for (int dx = 0; dx < f; dx++) s += rp[dx];
        }
        pp[tid] = s;
      }
      __syncthreads();
      if (tid < items) {
        double s = 0.0;
        for (int p2 = 0; p2 < P; p2++) s += pp[tid * P + p2];
        int cc = tid & 7, rem = tid >> 3;
        __hip_atomic_store(&rv_pub[((b << 8) + rem) * NC + co0 + cc],
                           s / (double)(f * f),
                           __ATOMIC_RELAXED, __HIP_MEMORY_SCOPE_AGENT);
      }
    }
    groupbar(&flags[(b << 4) + si * 2]);

    // ---------- argmin: rows jq::4 of batch b, ALL 4096 codes (R1 micro) ----
    {
      const int count = (ph2 > jq) ? ((ph2 - jq + 3) >> 2) : 0;  // local rows
      double* rvt = (double*)qreg;             // [64][32] staged rows (16 KB)
      double* wd  = (double*)(qreg + 16384);   // [16][8]
      int*    wi  = (int*)(qreg + 17408);      // [16][8]
      for (int t = tid; t < count * 32; t += TPB) {   // coalesced sc1 stage
        int m = t >> 5, k = t & 31;
        rvt[t] = __hip_atomic_load(&rv_pub[((b << 8) + jq + 4 * m) * NC + k],
                                   __ATOMIC_RELAXED, __HIP_MEMORY_SCOPE_AGENT);
      }
      __syncthreads();
      for (int m0 = 0; m0 < count; m0 += 8) {
        double best[8]; int bidx[8];
        #pragma unroll
        for (int j = 0; j < 8; j++) { best[j] = 1e300; bidx[j] = 0; }
        #pragma unroll
        for (int pass = 0; pass < 2; pass++) { // 1024 thr x 2 codes x 2 passes
          int e0 = pass * 2048 + (tid << 1);
          double acc[8][2];
          #pragma unroll
          for (int j = 0; j < 8; j++) { acc[j][0] = 0.0; acc[j][1] = 0.0; }
          #pragma unroll 4
          for (int k = 0; k < NC; k++) {
            float2 e2 = *(const float2*)(emb_t + k * NE + e0);  // L2, coalesced
            double d0 = e2.x, d1 = e2.y;
            #pragma unroll
            for (int j = 0; j < 8; j++) {
              double rj = rvt[(m0 + j) * 32 + k];   // LDS broadcast
              acc[j][0] += rj * d0; acc[j][1] += rj * d1;
            }
          }
          #pragma unroll
          for (int v = 0; v < 2; v++) {        // ascending code id
            double esq = emb_sq[e0 + v];
            #pragma unroll
            for (int j = 0; j < 8; j++) {
              double d = esq - 2.0 * acc[j][v];
              if (d < best[j]) { best[j] = d; bidx[j] = e0 + v; }
            }
          }
        }
        #pragma unroll
        for (int j = 0; j < 8; j++) {
          double d = best[j]; int bi2 = bidx[j];
          #pragma unroll
          for (int off = 32; off >= 1; off >>= 1) {
            double od = __shfl_xor(d, off, 64);
            int oi = __shfl_xor(bi2, off, 64);
            if (od < d || (od == d && oi < bi2)) { d = od; bi2 = oi; }
          }
          best[j] = d; bidx[j] = bi2;
        }
        int wave = tid >> 6, lane = tid & 63;
        if (lane == 0) {
          #pragma unroll
          for (int j = 0; j < 8; j++) { wd[wave*8+j] = best[j]; wi[wave*8+j] = bidx[j]; }
        }
        __syncthreads();
        if (tid < 8 && m0 + tid < count) {
          double d = wd[tid]; int bi2 = wi[tid];
          #pragma unroll
          for (int w2 = 1; w2 < 16; w2++) {
            double od = wd[w2 * 8 + tid]; int oi = wi[w2 * 8 + tid];
            if (od < d || (od == d && oi < bi2)) { d = od; bi2 = oi; }
          }
          int n = jq + 4 * (m0 + tid);         // global row in [0, ph2)
          __hip_atomic_store(&win[(b << 8) + n], bi2,
                             __ATOMIC_RELAXED, __HIP_MEMORY_SCOPE_AGENT);
          out_idx[b * IDXW + offs[si] + n] = (float)bi2;
        }
        __syncthreads();                       // wd/wi reused next chunk
      }
    }
    groupbar(&flags[(b << 4) + si * 2 + 1]);

    // ---------- gather winners ----------
    unsigned short* fidx = (unsigned short*)(ttreg + 8192);  // [256]
    if (tid < ph2)
      fidx[tid] = (unsigned short)__hip_atomic_load(&win[(b << 8) + tid],
                      __ATOMIC_RELAXED, __HIP_MEMORY_SCOPE_AGENT);
    __syncthreads();

    // ---------- upsample: full 32-ch q in LDS (redundant x4, cheap) ---------
    float* simg = (float*)qreg;                // [32][256] f32
    if (si == 4) {
      for (int i = tid; i < 32 * 256; i += TPB)
        simg[i] = emb[(int)fidx[i & 255] * NC + (i >> 8)];
    } else {
      double* wtab = (double*)(ttreg + 8704);  // [16][4]
      int* itab = (int*)(ttreg + 9216);        // [16]
      double scale = (double)ph / 16.0;
      if (tid < 64) {
        int oy = tid >> 2, kk = tid & 3;
        double src = ((double)oy + 0.5) * scale - 0.5;
        double fi = floor(src);
        if (kk == 0) itab[oy] = (int)fi;
        wtab[tid] = cubicw(src - fi - (double)(kk - 1));
      }
      __syncthreads();
      int CH = (si == 3) ? 16 : 32, nhalf = (si == 3) ? 2 : 1;
      float* qs = (float*)(qreg + 28672);      // <=4 KB (aliases simg ch28-31)
      float* tt = (float*)ttreg;               // <=8 KB H-pass intermediate
      for (int half = 0; half < nhalf; half++) {
        int c0 = half * CH;
        for (int i = tid; i < CH * ph2; i += TPB) {
          int cc = i / ph2, rem = i - cc * ph2;
          qs[i] = emb[(int)fidx[rem] * NC + c0 + cc];
        }
        __syncthreads();
        for (int i = tid; i < CH * 16 * ph; i += TPB) {   // H pass
          int x = i % ph, oy = (i / ph) & 15, cc = i / (16 * ph);
          int i0 = itab[oy];
          double s = 0.0;
          #pragma unroll
          for (int k = 0; k < 4; k++) {
            int iy = min(max(i0 + k - 1, 0), ph - 1);
            s += wtab[oy * 4 + k] * (double)qs[(cc * ph + iy) * ph + x];
          }
          tt[i] = (float)s;
        }
        __syncthreads();
        for (int i = tid; i < CH * 256; i += TPB) {       // W pass
          int ox = i & 15, oy = (i >> 4) & 15, cc = i >> 8;
          int i0 = itab[ox];
          double s = 0.0;
          #pragma unroll
          for (int k = 0; k < 4; k++) {
            int ix = min(max(i0 + k - 1, 0), ph - 1);
            s += wtab[ox * 4 + k] * (double)tt[(cc * 16 + oy) * ph + ix];
          }
          simg[(c0 + cc) * 256 + oy * 16 + ox] = (float)s;
        }
        __syncthreads();
      }
    }
    __syncthreads();

    // ---------- phi: 0.5*x + 0.5*(conv3x3(x)+b); own channels; zres LDS -----
    {
      float* lw = (float*)ttreg;               // [8][32][9] = 9216 B
      const float* wsrc = phi_w + (pis[si] * NC + co0) * NC * 9;
      for (int i = tid; i < 8 * NC * 9; i += TPB) lw[i] = wsrc[i];
      __syncthreads();
      int pix = tid & 255, sub = tid >> 8;     // 4 subs x 2 co = 8 co
      int x = pix & 15, y = pix >> 4;
      double a0 = 0.0, a1 = 0.0;
      for (int ci = 0; ci < NC; ci++) {
        double wv[9];
        #pragma unroll
        for (int ky = 0; ky < 3; ky++) {
          int yy = y + ky - 1;
          #pragma unroll
          for (int kx = 0; kx < 3; kx++) {
            int xx = x + kx - 1;
            wv[ky * 3 + kx] = (yy >= 0 && yy < NH && xx >= 0 && xx < NW)
                              ? (double)simg[(ci << 8) + yy * 16 + xx] : 0.0;
          }
        }
        const float* wp0 = lw + ((sub * 2 + 0) * NC + ci) * 9;  // wave-uniform
        const float* wp1 = lw + ((sub * 2 + 1) * NC + ci) * 9;
        #pragma unroll
        for (int k = 0; k < 9; k++) a0 += wv[k] * (double)wp0[k];
        #pragma unroll
        for (int k = 0; k < 9; k++) a1 += wv[k] * (double)wp1[k];
      }
      double lsum = 0.0;
      #pragma unroll
      for (int jj = 0; jj < 2; jj++) {
        int col = sub * 2 + jj;
        double aj = jj ? a1 : a0;
        double val = (double)simg[((co0 + col) << 8) + pix] * 0.5
                   + (aj + (double)phi_b[pis[si] * NC + co0 + col]) * 0.5;
        int li = (col << 8) + pix;
        double zr = zres[li] - val;
        zres[li] = zr;
        if (si == 4) {
          int gi = ((b * NC + co0 + col) << 8) + pix;
          out_zhat[gi] = (float)((double)z[gi] - zr);
        }
        lsum += zr * zr;                       // z_hat - z == -z_res
      }
      __syncthreads();                         // simg consumed
      double* red = (double*)qreg;
      red[tid] = lsum; __syncthreads();
      for (int s = 512; s > 0; s >>= 1) {
        if (tid < s) red[tid] += red[tid + s];
        __syncthreads();
      }
      if (tid == 0) bloss += red[0];
      __syncthreads();
    }
  }

  // ---------- global loss: one f64 atomic per block; last arriver writes ----
  if (tid == 0) {
    double old = unsafeAtomicAdd(loss_d, bloss); (void)old;
    asm volatile("s_waitcnt vmcnt(0)" ::: "memory");
    unsigned n = __hip_atomic_fetch_add(cnt, 1u, __ATOMIC_RELAXED,
                                        __HIP_MEMORY_SCOPE_AGENT);
    if (n == GRID - 1u) {
      double tot = __hip_atomic_load(loss_d, __ATOMIC_RELAXED,
                                     __HIP_MEMORY_SCOPE_AGENT);
      *out_loss = (float)(tot * (1.25 / (5.0 * (double)NTOT)));
    }
  }
}

extern "C" void kernel_launch(void* const* d_in, const int* in_sizes, int n_in,
                              void* d_out, int out_size, void* d_ws, size_t ws_size,
                              hipStream_t stream) {
  const float* z     = (const float*)d_in[0];   // [64,32,16,16]
  const float* emb   = (const float*)d_in[1];   // [4096,32]
  const float* phi_w = (const float*)d_in[2];   // [4,32,32,3,3]
  const float* phi_b = (const float*)d_in[3];   // [4,32]

  float* out      = (float*)d_out;
  float* out_zhat = out;
  float* out_loss = out + NTOT;
  float* out_idx  = out + NTOT + 1;             // [64,341] as floats

  double* ws      = (double*)d_ws;
  double* rv_pub  = ws;                          // 64*256*32 f64 = 4 MB
  double* emb_sq  = rv_pub + 64 * 256 * NC;      // 4096 f64
  double* loss_d  = emb_sq + NE;                 // 1 f64
  float*  emb_t   = (float*)(loss_d + 1);        // 131072 f32
  int*    win     = (int*)(emb_t + NE * NC);     // 64*256 int
  unsigned* cnt   = (unsigned*)(win + NB * 256); // 1
  unsigned* gbar  = cnt + 1;                     // 1
  unsigned* flags = gbar + 1;                    // 64*16 one-shot cells

  k_fused<<<GRID, TPB, 0, stream>>>(z, emb, phi_w, phi_b,
                                    rv_pub, emb_sq, loss_d, emb_t,
                                    win, cnt, gbar, flags,
                                    out_zhat, out_loss, out_idx);
}

// Round 4
// 555.794 us; speedup vs baseline: 25.2354x; 1.0854x over previous
//
#include <hip/hip_runtime.h>

#define NB 64
#define NC 32
#define NH 16
#define NW 16
#define NE 4096
#define NTOT (NB*NC*NH*NW)   // 524288
#define IDXW 341             // 1+4+16+64+256
#define GRID 256
#define TPB 1024

typedef float f32x2 __attribute__((ext_vector_type(2)));
typedef float f32x4 __attribute__((ext_vector_type(4)));

__device__ __forceinline__ f32x2 pkfma(f32x2 a, f32x2 b, f32x2 c) {
#if __has_builtin(__builtin_elementwise_fma)
  return __builtin_elementwise_fma(a, b, c);
#else
  return (f32x2){fmaf(a.x, b.x, c.x), fmaf(a.y, b.y, c.y)};
#endif
}

__device__ __forceinline__ double cubicw(double x) {
  const double A = -0.75;
  x = fabs(x);
  if (x <= 1.0) return ((A + 2.0) * x - (A + 3.0)) * x * x + 1.0;
  if (x < 2.0)  return A * (((x - 5.0) * x + 8.0) * x - 4.0);
  return 0.0;
}

// monotonic u32 key: smaller float <=> smaller key (handles negatives)
__device__ __forceinline__ unsigned monokey(float f) {
  unsigned u = __float_as_uint(f);
  return (u & 0x80000000u) ? ~u : (u | 0x80000000u);
}

__device__ __forceinline__ unsigned aload(unsigned* p) {
  return __hip_atomic_load(p, __ATOMIC_RELAXED, __HIP_MEMORY_SCOPE_AGENT);
}

// 4-party group barrier, fence-free (proven R2/R3): sc0sc1 publishes are
// coherent at IF$; __syncthreads drains vmcnt before arrive.
__device__ __forceinline__ void groupbar(unsigned* fl) {
  __syncthreads();
  if (threadIdx.x == 0) {
    __hip_atomic_fetch_add(fl, 1u, __ATOMIC_RELAXED, __HIP_MEMORY_SCOPE_AGENT);
    while (aload(fl) < 4u) __builtin_amdgcn_s_sleep(4);
  }
  __syncthreads();
}

__global__ __launch_bounds__(TPB, 4) void k_fused(
    const float* __restrict__ z, const float* __restrict__ emb,
    const float* __restrict__ phi_w, const float* __restrict__ phi_b,
    double* __restrict__ rv64, double* __restrict__ emb_sq,
    double* __restrict__ loss_d, float* __restrict__ emb_ti,
    float* __restrict__ emb_sq32, int* __restrict__ win,
    unsigned* __restrict__ cnt, unsigned* __restrict__ gbar,
    unsigned* __restrict__ flags,
    float* __restrict__ out_zhat, float* __restrict__ out_loss,
    float* __restrict__ out_idx)
{
  __shared__ double lds[8192];                 // 64 KB
  double* zres = lds;                          // [8][256] f64, persistent [0,16K)
  char* qreg   = (char*)lds + 16384;           // 32 KB multi-use [16K,48K)
  char* ttreg  = (char*)lds + 49152;           // 16 KB multi-use [48K,64K)

  const int tid = threadIdx.x;
  const int b = blockIdx.x >> 2, jq = blockIdx.x & 3;
  const int co0 = jq * 8;

  // idempotent CAS-init of poisoned (0xAA) sync cells
  if (tid < 16) atomicCAS(&flags[(b << 4) + tid], 0xAAAAAAAAu, 0u);
  if (tid == 0) {
    atomicCAS((unsigned long long*)loss_d, 0xAAAAAAAAAAAAAAAAull, 0ull);
    atomicCAS(cnt, 0xAAAAAAAAu, 0u);
    atomicCAS(gbar, 0xAAAAAAAAu, 0u);
  }

  // ---------- setup: zres <- z slice; emb_ti (k-pair interleave) + emb_sq ---
  #pragma unroll
  for (int t = 0; t < 2; t++) {
    int i = t * TPB + tid;
    zres[i] = (double)z[((b * NC + co0) << 8) + i];
  }
  {
    int c0 = blockIdx.x * 16;                  // 16 codes per block
    if (tid < 512) {
      int cl = tid >> 5, k = tid & 31;
      // layout: emb_ti[k2*8192 + code*2 + (k&1)]
      emb_ti[(k >> 1) * 8192 + (c0 + cl) * 2 + (k & 1)] = emb[(c0 + cl) * NC + k];
    }
    if (tid < 16) {
      const float* er = emb + (c0 + tid) * NC;
      double s = 0.0;
      #pragma unroll
      for (int j = 0; j < 8; j++)
        s += (double)er[4*j]*er[4*j] + (double)er[4*j+1]*er[4*j+1]
           + (double)er[4*j+2]*er[4*j+2] + (double)er[4*j+3]*er[4*j+3];
      emb_sq[c0 + tid] = s;
      emb_sq32[c0 + tid] = (float)s;
    }
  }
  // one-time FENCED tree barrier (only threadfence pair in the kernel):
  // publishes emb_ti/emb_sq/emb_sq32 for normal L2-cached reads thereafter.
  __syncthreads();
  if (tid == 0) {
    __threadfence();                           // release (wb L2)
    __hip_atomic_fetch_add(&flags[(b << 4) + 15], 1u, __ATOMIC_RELAXED,
                           __HIP_MEMORY_SCOPE_AGENT);
    if (jq == 0) {
      while (aload(&flags[(b << 4) + 15]) < 4u) __builtin_amdgcn_s_sleep(2);
      __hip_atomic_fetch_add(gbar, 1u, __ATOMIC_RELAXED,
                             __HIP_MEMORY_SCOPE_AGENT);
      while (aload(gbar) < 64u) __builtin_amdgcn_s_sleep(8);
      __hip_atomic_store(&flags[(b << 4) + 14], 1u, __ATOMIC_RELAXED,
                         __HIP_MEMORY_SCOPE_AGENT);
    } else {
      while (aload(&flags[(b << 4) + 14]) < 1u) __builtin_amdgcn_s_sleep(4);
    }
    __threadfence();                           // acquire (inv L2)
  }
  __syncthreads();

  double bloss = 0.0;
  // ticks = np.linspace(1/12, 11/12, 4) f64: si=2 tie breaks to pi=2
  const int pis[5]  = {0, 1, 2, 2, 3};
  const int offs[5] = {0, 1, 5, 21, 85};

  for (int si = 0; si < 5; si++) {
    const int ph = 1 << si, f = NH / ph, ph2 = ph * ph;
    const int idx_off = offs[si];

    // ---------- pool own 8 channels (f64) -> publish rv64 [b][n][c] ---------
    if (si == 4) {
      #pragma unroll
      for (int t = 0; t < 2; t++) {
        int i = t * TPB + tid;
        int pix = i >> 3, cc = i & 7;          // coalesced publish
        __hip_atomic_store(&rv64[(((b << 8) + pix) << 5) + co0 + cc],
                           zres[cc * 256 + pix],
                           __ATOMIC_RELAXED, __HIP_MEMORY_SCOPE_AGENT);
      }
    } else {
      double* pp = (double*)qreg;              // [work] partials  [16K,24K)
      double* pooled = (double*)(qreg + 8192); // [8][ph2]         [24K,28K)
      const int P = (f >= 8) ? 8 : f;          // si0:8 si1:8 si2:4 si3:2
      const int lP = (f >= 8) ? 3 : ((f == 4) ? 2 : 1);
      const int items = 8 * ph2, work = items * P, dpp = f / P;
      if (tid < work) {
        int it = tid >> lP, part = tid & (P - 1);
        int cc = it >> (2 * si), rem = it & (ph2 - 1);
        int y = rem >> si, x = rem & (ph - 1);
        const double* basep = zres + cc * 256 + (y * f) * 16 + x * f;
        double s = 0.0;
        for (int dy = part * dpp; dy < part * dpp + dpp; dy++) {
          const double* rp = basep + dy * 16;
          #pragma unroll 4
          for (int dx = 0; dx < f; dx++) s += rp[dx];
        }
        pp[tid] = s;
      }
      __syncthreads();
      if (tid < items) {
        double s = 0.0;
        for (int p2 = 0; p2 < P; p2++) s += pp[(tid << lP) + p2];
        pooled[tid] = s / (double)(f * f);     // tid = cc*ph2+rem
      }
      __syncthreads();
      if (tid < items) {
        int rem = tid >> 3, cc = tid & 7;      // coalesced publish
        __hip_atomic_store(&rv64[(((b << 8) + rem) << 5) + co0 + cc],
                           pooled[cc * ph2 + rem],
                           __ATOMIC_RELAXED, __HIP_MEMORY_SCOPE_AGENT);
      }
    }
    groupbar(&flags[(b << 4) + si * 2]);

    // ---------- argmin: rows jq::4, all 4096 codes; f32 scan + f64 rescore --
    {
      const int count = (ph2 > jq) ? ((ph2 - jq + 3) >> 2) : 0;
      float*  rvt32 = (float*)qreg;                          // [64][32] 8KB
      double* rvt64 = (double*)(qreg + 8192);                // [64][32] 16KB
      unsigned long long* wdu = (unsigned long long*)(qreg + 24576); // 2KB
      unsigned short* cand = (unsigned short*)(qreg + 26624);        // 256B
      // stage 64 rows (padded; garbage rows finite & never output)
      for (int t = tid; t < 2048; t += TPB) {
        int m = t >> 5, k = t & 31;
        double v = __hip_atomic_load(&rv64[(((b << 8) + jq + 4 * m) << 5) + k],
                                     __ATOMIC_RELAXED, __HIP_MEMORY_SCOPE_AGENT);
        rvt64[t] = v;
        rvt32[t] = (float)v;
      }
      __syncthreads();
      if (count) {
        for (int m0 = 0; m0 < count; m0 += 8) {
          float b1[8], b2[8]; int i1[8], i2[8];
          #pragma unroll
          for (int j = 0; j < 8; j++) {
            b1[j] = INFINITY; b2[j] = INFINITY; i1[j] = 0; i2[j] = 0;
          }
          #pragma unroll
          for (int pass = 0; pass < 2; pass++) {  // 1024 thr x 2 codes x 2
            const int e0 = pass * 2048 + (tid << 1);
            f32x2 acc[8];
            #pragma unroll
            for (int j = 0; j < 8; j++) acc[j] = (f32x2){0.f, 0.f};
            const f32x4* __restrict__ ebase = (const f32x4*)emb_ti + (e0 >> 1);
            #pragma unroll 4
            for (int k2 = 0; k2 < 16; k2++) {
              f32x4 E = ebase[k2 * 2048];          // coalesced dwordx4
              #pragma unroll
              for (int j = 0; j < 8; j++) {
                f32x2 r2 = *(const f32x2*)(rvt32 + ((m0 + j) << 5) + (k2 << 1));
                acc[j] = pkfma((f32x2){r2.x, r2.x}, (f32x2){E.x, E.z}, acc[j]);
                acc[j] = pkfma((f32x2){r2.y, r2.y}, (f32x2){E.y, E.w}, acc[j]);
              }
            }
            f32x2 es = *(const f32x2*)(emb_sq32 + e0);
            #pragma unroll
            for (int j = 0; j < 8; j++) {
              float d0 = es.x - 2.f * acc[j].x;
              float d1 = es.y - 2.f * acc[j].y;
              if (d0 < b1[j]) { b2[j]=b1[j]; i2[j]=i1[j]; b1[j]=d0; i1[j]=e0; }
              else if (d0 < b2[j]) { b2[j] = d0; i2[j] = e0; }
              if (d1 < b1[j]) { b2[j]=b1[j]; i2[j]=i1[j]; b1[j]=d1; i1[j]=e0+1; }
              else if (d1 < b2[j]) { b2[j] = d1; i2[j] = e0 + 1; }
            }
          }
          const int lane = tid & 63, wv_ = tid >> 6;
          #pragma unroll
          for (int j = 0; j < 8; j++) {          // exact top-2 pair butterfly
            unsigned long long p1 =
                ((unsigned long long)monokey(b1[j]) << 32) | (unsigned)i1[j];
            unsigned long long p2 =
                ((unsigned long long)monokey(b2[j]) << 32) | (unsigned)i2[j];
            #pragma unroll
            for (int off = 32; off >= 1; off >>= 1) {
              unsigned long long q1 = __shfl_xor(p1, off, 64);
              unsigned long long q2 = __shfl_xor(p2, off, 64);
              unsigned long long lo = p1 < q1 ? p1 : q1;
              unsigned long long hi = p1 < q1 ? q1 : p1;
              unsigned long long m2 = p2 < q2 ? p2 : q2;
              p1 = lo;
              p2 = hi < m2 ? hi : m2;
            }
            if (lane == 0) {
              wdu[(wv_ << 4) + (j << 1)] = p1;
              wdu[(wv_ << 4) + (j << 1) + 1] = p2;
            }
          }
          __syncthreads();
          if (tid < 8 && m0 + tid < count) {     // cross-wave top-2 merge
            unsigned long long G1 = ~0ull, G2 = ~0ull;
            #pragma unroll
            for (int w = 0; w < 16; w++) {
              unsigned long long a1 = wdu[(w << 4) + (tid << 1)];
              unsigned long long a2 = wdu[(w << 4) + (tid << 1) + 1];
              if (a1 < G1) { G2 = (G1 < a2 ? G1 : a2); G1 = a1; }
              else if (a1 < G2) G2 = a1;
            }
            cand[((m0 + tid) << 1)]     = (unsigned short)(G1 & 0xFFFFu);
            cand[((m0 + tid) << 1) + 1] = (unsigned short)(G2 & 0xFFFFu);
          }
          __syncthreads();                       // wdu reused next chunk
        }
        // f64 rescore of the exact f32-top-2 -> final winner (matches R3)
        if (tid < 2 * count) {
          int m = tid >> 1, cs = tid & 1;
          int c = cand[(m << 1) + cs];
          const float* er = emb + (c << 5);
          double dot = 0.0;
          #pragma unroll
          for (int k = 0; k < 32; k++)
            dot = fma(rvt64[(m << 5) + k], (double)er[k], dot);
          double d = emb_sq[c] - 2.0 * dot;
          double doth = __shfl_xor(d, 1, 64);
          int coth = __shfl_xor(c, 1, 64);
          if (cs == 0) {
            int wc = (doth < d || (doth == d && coth < c)) ? coth : c;
            int n = jq + (m << 2);
            __hip_atomic_store(&win[(b << 8) + n], wc,
                               __ATOMIC_RELAXED, __HIP_MEMORY_SCOPE_AGENT);
            out_idx[b * IDXW + idx_off + n] = (float)wc;
          }
        }
      }
    }
    groupbar(&flags[(b << 4) + si * 2 + 1]);

    // ---------- gather winners ----------
    unsigned short* fidx = (unsigned short*)(ttreg + 12800);   // [256]
    if (tid < ph2)
      fidx[tid] = (unsigned short)__hip_atomic_load(&win[(b << 8) + tid],
                      __ATOMIC_RELAXED, __HIP_MEMORY_SCOPE_AGENT);
    __syncthreads();

    // ---------- upsample (f32): full 32-ch q in LDS (redundant x4) ----------
    float* simg = (float*)qreg;                // [32][256] f32, 32KB
    if (si == 4) {
      for (int i = tid; i < 32 * 256; i += TPB)
        simg[i] = emb[(int)fidx[i & 255] * NC + (i >> 8)];
    } else {
      float* wtab = (float*)(ttreg + 12288);   // [16][4] f32
      int* itab = (int*)(ttreg + 12544);       // [16]
      double scale = (double)ph / 16.0;
      if (tid < 64) {
        int oy = tid >> 2, kk = tid & 3;
        double src = ((double)oy + 0.5) * scale - 0.5;
        double fi = floor(src);
        if (kk == 0) itab[oy] = (int)fi;
        wtab[tid] = (float)cubicw(src - fi - (double)(kk - 1));
      }
      __syncthreads();
      int CH = (si == 3) ? 16 : 32, nhalf = (si == 3) ? 2 : 1;
      float* qs = (float*)(ttreg + 8192);      // <=4KB gather buf
      float* tt = (float*)ttreg;               // <=8KB H-pass intermediate
      for (int half = 0; half < nhalf; half++) {
        int c0 = half * CH;
        for (int i = tid; i < CH * ph2; i += TPB) {
          int cc = i >> (2 * si), rem = i & (ph2 - 1);
          qs[i] = emb[(int)fidx[rem] * NC + c0 + cc];
        }
        __syncthreads();
        for (int i = tid; i < CH * 16 * ph; i += TPB) {   // H pass (y)
          int x = i & (ph - 1), oy = (i >> si) & 15, cc = i >> (4 + si);
          int i0 = itab[oy];
          float s = 0.f;
          #pragma unroll
          for (int k = 0; k < 4; k++) {
            int iy = min(max(i0 + k - 1, 0), ph - 1);
            s = fmaf(wtab[oy * 4 + k], qs[(cc * ph + iy) * ph + x], s);
          }
          tt[i] = s;
        }
        __syncthreads();
        for (int i = tid; i < CH * 256; i += TPB) {       // W pass (x)
          int ox = i & 15, oy = (i >> 4) & 15, cc = i >> 8;
          int i0 = itab[ox];
          float s = 0.f;
          #pragma unroll
          for (int k = 0; k < 4; k++) {
            int ix = min(max(i0 + k - 1, 0), ph - 1);
            s = fmaf(wtab[ox * 4 + k], tt[(cc * 16 + oy) * ph + ix], s);
          }
          simg[(c0 + cc) * 256 + oy * 16 + ox] = s;
        }
        __syncthreads();
      }
    }
    __syncthreads();

    // ---------- phi (packed f32): 0.5*x + 0.5*(conv3x3(x)+b); zres f64 ------
    {
      float* lw2 = (float*)ttreg;              // co-pair interleaved, 9216B
      const float* wsrc = phi_w + (pis[si] * NC + co0) * NC * 9;
      for (int i = tid; i < 2304; i += TPB) {
        int co = i / 288, rem = i - co * 288;  // rem = ci*9+k
        lw2[(((co >> 1) * 288 + rem) << 1) + (co & 1)] = wsrc[i];
      }
      __syncthreads();
      int pix = tid & 255, sub = tid >> 8;     // 4 subs x 2 co = 8 co
      int x = pix & 15, y = pix >> 4;
      f32x2 a = {0.f, 0.f};
      const f32x2* wp = (const f32x2*)lw2 + sub * 288;
      for (int ci = 0; ci < NC; ci++) {
        float wv[9];
        #pragma unroll
        for (int ky = 0; ky < 3; ky++) {
          int yy = y + ky - 1;
          #pragma unroll
          for (int kx = 0; kx < 3; kx++) {
            int xx = x + kx - 1;
            wv[ky * 3 + kx] = (yy >= 0 && yy < NH && xx >= 0 && xx < NW)
                              ? simg[(ci << 8) + yy * 16 + xx] : 0.f;
          }
        }
        #pragma unroll
        for (int k = 0; k < 9; k++)
          a = pkfma((f32x2){wv[k], wv[k]}, wp[ci * 9 + k], a);
      }
      double lsum = 0.0;
      #pragma unroll
      for (int jj = 0; jj < 2; jj++) {
        int col = (sub << 1) + jj;
        float aj = jj ? a.y : a.x;
        float val = simg[((co0 + col) << 8) + pix] * 0.5f
                  + (aj + phi_b[pis[si] * NC + co0 + col]) * 0.5f;
        int li = (col << 8) + pix;
        double zr = zres[li] - (double)val;
        zres[li] = zr;
        if (si == 4) {
          int gi = ((b * NC + co0 + col) << 8) + pix;
          out_zhat[gi] = (float)((double)z[gi] - zr);
        }
        lsum += zr * zr;                       // z_hat - z == -z_res
      }
      __syncthreads();                         // simg consumed
      double* red = (double*)qreg;
      red[tid] = lsum; __syncthreads();
      for (int s = 512; s > 0; s >>= 1) {
        if (tid < s) red[tid] += red[tid + s];
        __syncthreads();
      }
      if (tid == 0) bloss += red[0];
      __syncthreads();
    }
  }

  // ---------- global loss: one f64 atomic per block; last arriver writes ----
  if (tid == 0) {
    double old = unsafeAtomicAdd(loss_d, bloss); (void)old;
    asm volatile("s_waitcnt vmcnt(0)" ::: "memory");
    unsigned n = __hip_atomic_fetch_add(cnt, 1u, __ATOMIC_RELAXED,
                                        __HIP_MEMORY_SCOPE_AGENT);
    if (n == GRID - 1u) {
      double tot = __hip_atomic_load(loss_d, __ATOMIC_RELAXED,
                                     __HIP_MEMORY_SCOPE_AGENT);
      *out_loss = (float)(tot * (1.25 / (5.0 * (double)NTOT)));
    }
  }
}

extern "C" void kernel_launch(void* const* d_in, const int* in_sizes, int n_in,
                              void* d_out, int out_size, void* d_ws, size_t ws_size,
                              hipStream_t stream) {
  const float* z     = (const float*)d_in[0];   // [64,32,16,16]
  const float* emb   = (const float*)d_in[1];   // [4096,32]
  const float* phi_w = (const float*)d_in[2];   // [4,32,32,3,3]
  const float* phi_b = (const float*)d_in[3];   // [4,32]

  float* out      = (float*)d_out;
  float* out_zhat = out;
  float* out_loss = out + NTOT;
  float* out_idx  = out + NTOT + 1;             // [64,341] as floats

  double* ws       = (double*)d_ws;
  double* rv64     = ws;                            // 64*256*32 f64 = 4 MB
  double* emb_sq   = rv64 + 64 * 256 * NC;          // 4096 f64
  double* loss_d   = emb_sq + NE;                   // 1 f64 (+1 pad for 16B)
  float*  emb_ti   = (float*)(loss_d + 2);          // 131072 f32 (16B aligned)
  float*  emb_sq32 = emb_ti + NE * NC;              // 4096 f32
  int*    win      = (int*)(emb_sq32 + NE);         // 64*256 int
  unsigned* cnt    = (unsigned*)(win + NB * 256);   // 1
  unsigned* gbar   = cnt + 1;                       // 1
  unsigned* flags  = gbar + 1;                      // 64*16 one-shot cells

  k_fused<<<GRID, TPB, 0, stream>>>(z, emb, phi_w, phi_b,
                                    rv64, emb_sq, loss_d, emb_ti, emb_sq32,
                                    win, cnt, gbar, flags,
                                    out_zhat, out_loss, out_idx);
}

// Round 5
// 435.564 us; speedup vs baseline: 32.2011x; 1.2760x over previous
//
#include <hip/hip_runtime.h>

#define NB 64
#define NC 32
#define NH 16
#define NW 16
#define NE 4096
#define NTOT (NB*NC*NH*NW)   // 524288
#define IDXW 341             // 1+4+16+64+256
#define GRID 256
#define TPB 1024

typedef float f32x2 __attribute__((ext_vector_type(2)));
typedef float f32x4 __attribute__((ext_vector_type(4)));

__device__ __forceinline__ f32x2 pkfma(f32x2 a, f32x2 b, f32x2 c) {
#if __has_builtin(__builtin_elementwise_fma)
  return __builtin_elementwise_fma(a, b, c);
#else
  return (f32x2){fmaf(a.x, b.x, c.x), fmaf(a.y, b.y, c.y)};
#endif
}

__device__ __forceinline__ double cubicw(double x) {
  const double A = -0.75;
  x = fabs(x);
  if (x <= 1.0) return ((A + 2.0) * x - (A + 3.0)) * x * x + 1.0;
  if (x < 2.0)  return A * (((x - 5.0) * x + 8.0) * x - 4.0);
  return 0.0;
}

// monotonic u32 key: smaller float <=> smaller key (handles negatives)
__device__ __forceinline__ unsigned monokey(float f) {
  unsigned u = __float_as_uint(f);
  return (u & 0x80000000u) ? ~u : (u | 0x80000000u);
}

__device__ __forceinline__ unsigned aload(unsigned* p) {
  return __hip_atomic_load(p, __ATOMIC_RELAXED, __HIP_MEMORY_SCOPE_AGENT);
}

// 4-party group barrier, fence-free (proven R2-R4): sc0sc1 publishes are
// coherent at IF$; __syncthreads drains vmcnt before arrive.
__device__ __forceinline__ void groupbar(unsigned* fl) {
  __syncthreads();
  if (threadIdx.x == 0) {
    __hip_atomic_fetch_add(fl, 1u, __ATOMIC_RELAXED, __HIP_MEMORY_SCOPE_AGENT);
    while (aload(fl) < 4u) __builtin_amdgcn_s_sleep(1);
  }
  __syncthreads();
}

// waves_per_eu(4,4): grid = 1 block/CU = 16 waves = exactly 4/SIMD, so a
// 128-VGPR budget costs zero occupancy. Without it the allocator pins 64
// VGPR (8-waves heuristic) and spills the scan state to scratch -> the
// ~100 MB/dispatch of unexplained symmetric HBM traffic in R1-R4.
__global__ __launch_bounds__(TPB)
__attribute__((amdgpu_waves_per_eu(4, 4)))
void k_fused(
    const float* __restrict__ z, const float* __restrict__ emb,
    const float* __restrict__ phi_w, const float* __restrict__ phi_b,
    double* __restrict__ rv64, double* __restrict__ emb_sq,
    double* __restrict__ loss_d, float* __restrict__ emb_ti,
    float* __restrict__ emb_sq32, int* __restrict__ win,
    unsigned* __restrict__ cnt, unsigned* __restrict__ gbar,
    unsigned* __restrict__ flags,
    float* __restrict__ out_zhat, float* __restrict__ out_loss,
    float* __restrict__ out_idx)
{
  __shared__ double lds[8192];                 // 64 KB
  double* zres = lds;                          // [8][256] f64, persistent [0,16K)
  char* qreg   = (char*)lds + 16384;           // 32 KB multi-use [16K,48K)
  char* ttreg  = (char*)lds + 49152;           // 16 KB multi-use [48K,64K)

  const int tid = threadIdx.x;
  // group = {b, b+64, b+128, b+192}: all == b (mod 8) -> same XCD under the
  // default bid%8 XCD round-robin -> exchange stays XCD-local.
  const int b = blockIdx.x & 63, jq = blockIdx.x >> 6;
  const int co0 = jq * 8;

  // idempotent CAS-init of poisoned (0xAA) sync cells
  if (tid < 16) atomicCAS(&flags[(b << 4) + tid], 0xAAAAAAAAu, 0u);
  if (tid == 0) {
    atomicCAS((unsigned long long*)loss_d, 0xAAAAAAAAAAAAAAAAull, 0ull);
    atomicCAS(cnt, 0xAAAAAAAAu, 0u);
    atomicCAS(gbar, 0xAAAAAAAAu, 0u);
  }

  // ---------- setup: zres <- z slice; emb_ti (k-pair interleave) + emb_sq ---
  #pragma unroll
  for (int t = 0; t < 2; t++) {
    int i = t * TPB + tid;
    zres[i] = (double)z[((b * NC + co0) << 8) + i];
  }
  {
    int c0 = blockIdx.x * 16;                  // 16 codes per block
    if (tid < 512) {
      int cl = tid >> 5, k = tid & 31;
      // layout: emb_ti[k2*8192 + code*2 + (k&1)]
      emb_ti[(k >> 1) * 8192 + (c0 + cl) * 2 + (k & 1)] = emb[(c0 + cl) * NC + k];
    }
    if (tid < 16) {
      const float* er = emb + (c0 + tid) * NC;
      double s = 0.0;
      #pragma unroll
      for (int j = 0; j < 8; j++)
        s += (double)er[4*j]*er[4*j] + (double)er[4*j+1]*er[4*j+1]
           + (double)er[4*j+2]*er[4*j+2] + (double)er[4*j+3]*er[4*j+3];
      emb_sq[c0 + tid] = s;
      emb_sq32[c0 + tid] = (float)s;
    }
  }
  // one-time FENCED tree barrier (only threadfence pair in the kernel):
  // publishes emb_ti/emb_sq/emb_sq32 for normal L2-cached reads thereafter.
  __syncthreads();
  if (tid == 0) {
    __threadfence();                           // release (wb L2)
    __hip_atomic_fetch_add(&flags[(b << 4) + 15], 1u, __ATOMIC_RELAXED,
                           __HIP_MEMORY_SCOPE_AGENT);
    if (jq == 0) {
      while (aload(&flags[(b << 4) + 15]) < 4u) __builtin_amdgcn_s_sleep(1);
      __hip_atomic_fetch_add(gbar, 1u, __ATOMIC_RELAXED,
                             __HIP_MEMORY_SCOPE_AGENT);
      while (aload(gbar) < 64u) __builtin_amdgcn_s_sleep(4);
      __hip_atomic_store(&flags[(b << 4) + 14], 1u, __ATOMIC_RELAXED,
                         __HIP_MEMORY_SCOPE_AGENT);
    } else {
      while (aload(&flags[(b << 4) + 14]) < 1u) __builtin_amdgcn_s_sleep(1);
    }
    __threadfence();                           // acquire (inv L2)
  }
  __syncthreads();

  double bloss = 0.0;
  // ticks = np.linspace(1/12, 11/12, 4) f64: si=2 tie breaks to pi=2
  const int pis[5]  = {0, 1, 2, 2, 3};
  const int offs[5] = {0, 1, 5, 21, 85};

  for (int si = 0; si < 5; si++) {
    const int ph = 1 << si, f = NH / ph, ph2 = ph * ph;
    const int idx_off = offs[si];

    // ---------- pool own 8 channels (f64) -> publish rv64 [b][n][c] ---------
    if (si == 4) {
      #pragma unroll
      for (int t = 0; t < 2; t++) {
        int i = t * TPB + tid;
        int pix = i >> 3, cc = i & 7;          // coalesced publish
        __hip_atomic_store(&rv64[(((b << 8) + pix) << 5) + co0 + cc],
                           zres[cc * 256 + pix],
                           __ATOMIC_RELAXED, __HIP_MEMORY_SCOPE_AGENT);
      }
    } else {
      double* pp = (double*)qreg;              // [work] partials  [16K,24K)
      double* pooled = (double*)(qreg + 8192); // [8][ph2]         [24K,28K)
      const int P = (f >= 8) ? 8 : f;          // si0:8 si1:8 si2:4 si3:2
      const int lP = (f >= 8) ? 3 : ((f == 4) ? 2 : 1);
      const int items = 8 * ph2, work = items * P, dpp = f / P;
      if (tid < work) {
        int it = tid >> lP, part = tid & (P - 1);
        int cc = it >> (2 * si), rem = it & (ph2 - 1);
        int y = rem >> si, x = rem & (ph - 1);
        const double* basep = zres + cc * 256 + (y * f) * 16 + x * f;
        double s = 0.0;
        for (int dy = part * dpp; dy < part * dpp + dpp; dy++) {
          const double* rp = basep + dy * 16;
          #pragma unroll 4
          for (int dx = 0; dx < f; dx++) s += rp[dx];
        }
        pp[tid] = s;
      }
      __syncthreads();
      if (tid < items) {
        double s = 0.0;
        for (int p2 = 0; p2 < P; p2++) s += pp[(tid << lP) + p2];
        pooled[tid] = s / (double)(f * f);     // tid = cc*ph2+rem
      }
      __syncthreads();
      if (tid < items) {
        int rem = tid >> 3, cc = tid & 7;      // coalesced publish
        __hip_atomic_store(&rv64[(((b << 8) + rem) << 5) + co0 + cc],
                           pooled[cc * ph2 + rem],
                           __ATOMIC_RELAXED, __HIP_MEMORY_SCOPE_AGENT);
      }
    }
    groupbar(&flags[(b << 4) + si * 2]);

    // ---------- argmin: rows jq::4, all 4096 codes ---------------------------
    // 4 codes/thread, single pass; j-rows in two groups of 4 (peak liveness
    // ~60 VGPR, fits even a 64-reg budget). f32 scan + exact-top-2 + f64
    // rescore (winner identical to full-f64 unless true argmin ranks 3rd+
    // in f32 across a 4096-code row -- and index outputs stay exact).
    {
      const int count = (ph2 > jq) ? ((ph2 - jq + 3) >> 2) : 0;
      float*  rvt32 = (float*)qreg;                          // [64][32] 8KB
      double* rvt64 = (double*)(qreg + 8192);                // [64][32] 16KB
      unsigned long long* wdu = (unsigned long long*)(qreg + 24576); // [16][16]
      unsigned short* cand = (unsigned short*)(qreg + 26624);        // [128]
      for (int t = tid; t < 2048; t += TPB) {  // stage 64 rows (padded rows
        int m = t >> 5, k = t & 31;            // finite garbage, never output)
        double v = __hip_atomic_load(&rv64[(((b << 8) + jq + 4 * m) << 5) + k],
                                     __ATOMIC_RELAXED, __HIP_MEMORY_SCOPE_AGENT);
        rvt64[t] = v;
        rvt32[t] = (float)v;
      }
      __syncthreads();
      if (count) {
        const int e0 = tid << 2;               // 4 consecutive codes
        const f32x4 es4 = *(const f32x4*)(emb_sq32 + e0);
        const int lane = tid & 63, wv_ = tid >> 6;
        for (int m0 = 0; m0 < count; m0 += 8) {
          #pragma unroll
          for (int jg = 0; jg < 2; jg++) {
            f32x4 acc[4];
            #pragma unroll
            for (int j = 0; j < 4; j++) acc[j] = (f32x4){0.f, 0.f, 0.f, 0.f};
            const f32x4* __restrict__ eb = (const f32x4*)emb_ti + (tid << 1);
            #pragma unroll 4
            for (int k2 = 0; k2 < 16; k2++) {
              f32x4 E0 = eb[k2 * 2048];        // codes e0..e0+1, k pair
              f32x4 E1 = eb[k2 * 2048 + 1];    // codes e0+2..e0+3
              #pragma unroll
              for (int j = 0; j < 4; j++) {
                f32x2 r2 = *(const f32x2*)(rvt32 + ((m0 + jg * 4 + j) << 5)
                                           + (k2 << 1));
                f32x2 lo = {acc[j].x, acc[j].y}, hi = {acc[j].z, acc[j].w};
                lo = pkfma((f32x2){r2.x, r2.x}, (f32x2){E0.x, E0.z}, lo);
                lo = pkfma((f32x2){r2.y, r2.y}, (f32x2){E0.y, E0.w}, lo);
                hi = pkfma((f32x2){r2.x, r2.x}, (f32x2){E1.x, E1.z}, hi);
                hi = pkfma((f32x2){r2.y, r2.y}, (f32x2){E1.y, E1.w}, hi);
                acc[j] = (f32x4){lo.x, lo.y, hi.x, hi.y};
              }
            }
            #pragma unroll
            for (int j = 0; j < 4; j++) {      // exact top-2, ascending codes
              float d0 = es4.x - 2.f * acc[j].x;
              float d1 = es4.y - 2.f * acc[j].y;
              float d2 = es4.z - 2.f * acc[j].z;
              float d3 = es4.w - 2.f * acc[j].w;
              float b1 = d0, b2; int i1 = e0, i2;
              if (d1 < b1) { b2 = b1; i2 = i1; b1 = d1; i1 = e0 + 1; }
              else         { b2 = d1; i2 = e0 + 1; }
              if (d2 < b1) { b2 = b1; i2 = i1; b1 = d2; i1 = e0 + 2; }
              else if (d2 < b2) { b2 = d2; i2 = e0 + 2; }
              if (d3 < b1) { b2 = b1; i2 = i1; b1 = d3; i1 = e0 + 3; }
              else if (d3 < b2) { b2 = d3; i2 = e0 + 3; }
              unsigned long long p1 =
                  ((unsigned long long)monokey(b1) << 32) | (unsigned)i1;
              unsigned long long p2 =
                  ((unsigned long long)monokey(b2) << 32) | (unsigned)i2;
              #pragma unroll
              for (int off = 32; off >= 1; off >>= 1) {  // top-2 butterfly
                unsigned long long q1 = __shfl_xor(p1, off, 64);
                unsigned long long q2 = __shfl_xor(p2, off, 64);
                unsigned long long lo = p1 < q1 ? p1 : q1;
                unsigned long long hi = p1 < q1 ? q1 : p1;
                unsigned long long m2 = p2 < q2 ? p2 : q2;
                p1 = lo;
                p2 = hi < m2 ? hi : m2;
              }
              if (lane == 0) {
                int row = (jg << 2) + j;
                wdu[(wv_ << 4) + (row << 1)]     = p1;
                wdu[(wv_ << 4) + (row << 1) + 1] = p2;
              }
            }
          }
          __syncthreads();
          if (tid < 8 && m0 + tid < count) {   // cross-wave top-2 merge
            unsigned long long G1 = ~0ull, G2 = ~0ull;
            #pragma unroll
            for (int w = 0; w < 16; w++) {
              unsigned long long a1 = wdu[(w << 4) + (tid << 1)];
              unsigned long long a2 = wdu[(w << 4) + (tid << 1) + 1];
              if (a1 < G1) { G2 = (G1 < a2 ? G1 : a2); G1 = a1; }
              else if (a1 < G2) G2 = a1;
            }
            cand[((m0 + tid) << 1)]     = (unsigned short)(G1 & 0xFFFFu);
            cand[((m0 + tid) << 1) + 1] = (unsigned short)(G2 & 0xFFFFu);
          }
          __syncthreads();                     // wdu reused next chunk
        }
        // f64 rescore of the exact f32-top-2 -> final winner
        if (tid < 2 * count) {
          int m = tid >> 1, cs = tid & 1;
          int c = cand[(m << 1) + cs];
          const float* er = emb + (c << 5);
          double dot = 0.0;
          #pragma unroll
          for (int k = 0; k < 32; k++)
            dot = fma(rvt64[(m << 5) + k], (double)er[k], dot);
          double d = emb_sq[c] - 2.0 * dot;
          double doth = __shfl_xor(d, 1, 64);
          int coth = __shfl_xor(c, 1, 64);
          if (cs == 0) {
            int wc = (doth < d || (doth == d && coth < c)) ? coth : c;
            int n = jq + (m << 2);
            __hip_atomic_store(&win[(b << 8) + n], wc,
                               __ATOMIC_RELAXED, __HIP_MEMORY_SCOPE_AGENT);
            out_idx[b * IDXW + idx_off + n] = (float)wc;
          }
        }
      }
    }
    groupbar(&flags[(b << 4) + si * 2 + 1]);

    // ---------- gather winners ----------
    unsigned short* fidx = (unsigned short*)(ttreg + 12800);   // [256]
    if (tid < ph2)
      fidx[tid] = (unsigned short)__hip_atomic_load(&win[(b << 8) + tid],
                      __ATOMIC_RELAXED, __HIP_MEMORY_SCOPE_AGENT);
    __syncthreads();

    // ---------- upsample (f32): full 32-ch q in LDS (redundant x4) ----------
    float* simg = (float*)qreg;                // [32][256] f32, 32KB
    if (si == 4) {
      for (int i = tid; i < 32 * 256; i += TPB)
        simg[i] = emb[(int)fidx[i & 255] * NC + (i >> 8)];
    } else {
      float* wtab = (float*)(ttreg + 12288);   // [16][4] f32
      int* itab = (int*)(ttreg + 12544);       // [16]
      double scale = (double)ph / 16.0;
      if (tid < 64) {
        int oy = tid >> 2, kk = tid & 3;
        double src = ((double)oy + 0.5) * scale - 0.5;
        double fi = floor(src);
        if (kk == 0) itab[oy] = (int)fi;
        wtab[tid] = (float)cubicw(src - fi - (double)(kk - 1));
      }
      __syncthreads();
      int CH = (si == 3) ? 16 : 32, nhalf = (si == 3) ? 2 : 1;
      float* qs = (float*)(ttreg + 8192);      // <=4KB gather buf
      float* tt = (float*)ttreg;               // <=8KB H-pass intermediate
      for (int half = 0; half < nhalf; half++) {
        int c0 = half * CH;
        for (int i = tid; i < CH * ph2; i += TPB) {
          int cc = i >> (2 * si), rem = i & (ph2 - 1);
          qs[i] = emb[(int)fidx[rem] * NC + c0 + cc];
        }
        __syncthreads();
        for (int i = tid; i < CH * 16 * ph; i += TPB) {   // H pass (y)
          int x = i & (ph - 1), oy = (i >> si) & 15, cc = i >> (4 + si);
          int i0 = itab[oy];
          float s = 0.f;
          #pragma unroll
          for (int k = 0; k < 4; k++) {
            int iy = min(max(i0 + k - 1, 0), ph - 1);
            s = fmaf(wtab[oy * 4 + k], qs[(cc * ph + iy) * ph + x], s);
          }
          tt[i] = s;
        }
        __syncthreads();
        for (int i = tid; i < CH * 256; i += TPB) {       // W pass (x)
          int ox = i & 15, oy = (i >> 4) & 15, cc = i >> 8;
          int i0 = itab[ox];
          float s = 0.f;
          #pragma unroll
          for (int k = 0; k < 4; k++) {
            int ix = min(max(i0 + k - 1, 0), ph - 1);
            s = fmaf(wtab[ox * 4 + k], tt[(cc * 16 + oy) * ph + ix], s);
          }
          simg[(c0 + cc) * 256 + oy * 16 + ox] = s;
        }
        __syncthreads();
      }
    }
    __syncthreads();

    // ---------- phi (packed f32): 0.5*x + 0.5*(conv3x3(x)+b); zres f64 ------
    {
      float* lw2 = (float*)ttreg;              // co-pair interleaved, 9216B
      const float* wsrc = phi_w + (pis[si] * NC + co0) * NC * 9;
      for (int i = tid; i < 2304; i += TPB) {
        int co = i / 288, rem = i - co * 288;  // rem = ci*9+k
        lw2[(((co >> 1) * 288 + rem) << 1) + (co & 1)] = wsrc[i];
      }
      __syncthreads();
      int pix = tid & 255, sub = tid >> 8;     // 4 subs x 2 co = 8 co
      int x = pix & 15, y = pix >> 4;
      f32x2 a = {0.f, 0.f};
      const f32x2* wp = (const f32x2*)lw2 + sub * 288;
      for (int ci = 0; ci < NC; ci++) {
        float wv[9];
        #pragma unroll
        for (int ky = 0; ky < 3; ky++) {
          int yy = y + ky - 1;
          #pragma unroll
          for (int kx = 0; kx < 3; kx++) {
            int xx = x + kx - 1;
            wv[ky * 3 + kx] = (yy >= 0 && yy < NH && xx >= 0 && xx < NW)
                              ? simg[(ci << 8) + yy * 16 + xx] : 0.f;
          }
        }
        #pragma unroll
        for (int k = 0; k < 9; k++)
          a = pkfma((f32x2){wv[k], wv[k]}, wp[ci * 9 + k], a);
      }
      double lsum = 0.0;
      #pragma unroll
      for (int jj = 0; jj < 2; jj++) {
        int col = (sub << 1) + jj;
        float aj = jj ? a.y : a.x;
        float val = simg[((co0 + col) << 8) + pix] * 0.5f
                  + (aj + phi_b[pis[si] * NC + co0 + col]) * 0.5f;
        int li = (col << 8) + pix;
        double zr = zres[li] - (double)val;
        zres[li] = zr;
        if (si == 4) {
          int gi = ((b * NC + co0 + col) << 8) + pix;
          out_zhat[gi] = (float)((double)z[gi] - zr);
        }
        lsum += zr * zr;                       // z_hat - z == -z_res
      }
      __syncthreads();                         // simg consumed
      // shuffle-based loss reduction (2 syncthreads instead of 10)
      #pragma unroll
      for (int off = 32; off >= 1; off >>= 1)
        lsum += __shfl_xor(lsum, off, 64);
      double* red = (double*)qreg;
      if ((tid & 63) == 0) red[tid >> 6] = lsum;
      __syncthreads();
      if (tid < 16) {
        double v = red[tid];
        #pragma unroll
        for (int off = 8; off >= 1; off >>= 1) v += __shfl_xor(v, off, 16);
        if (tid == 0) bloss += v;
      }
      __syncthreads();
    }
  }

  // ---------- global loss: one f64 atomic per block; last arriver writes ----
  if (tid == 0) {
    double old = unsafeAtomicAdd(loss_d, bloss); (void)old;
    asm volatile("s_waitcnt vmcnt(0)" ::: "memory");
    unsigned n = __hip_atomic_fetch_add(cnt, 1u, __ATOMIC_RELAXED,
                                        __HIP_MEMORY_SCOPE_AGENT);
    if (n == GRID - 1u) {
      double tot = __hip_atomic_load(loss_d, __ATOMIC_RELAXED,
                                     __HIP_MEMORY_SCOPE_AGENT);
      *out_loss = (float)(tot * (1.25 / (5.0 * (double)NTOT)));
    }
  }
}

extern "C" void kernel_launch(void* const* d_in, const int* in_sizes, int n_in,
                              void* d_out, int out_size, void* d_ws, size_t ws_size,
                              hipStream_t stream) {
  const float* z     = (const float*)d_in[0];   // [64,32,16,16]
  const float* emb   = (const float*)d_in[1];   // [4096,32]
  const float* phi_w = (const float*)d_in[2];   // [4,32,32,3,3]
  const float* phi_b = (const float*)d_in[3];   // [4,32]

  float* out      = (float*)d_out;
  float* out_zhat = out;
  float* out_loss = out + NTOT;
  float* out_idx  = out + NTOT + 1;             // [64,341] as floats

  double* ws       = (double*)d_ws;
  double* rv64     = ws;                            // 64*256*32 f64 = 4 MB
  double* emb_sq   = rv64 + 64 * 256 * NC;          // 4096 f64
  double* loss_d   = emb_sq + NE;                   // 1 f64 (+1 pad for 16B)
  float*  emb_ti   = (float*)(loss_d + 2);          // 131072 f32 (16B aligned)
  float*  emb_sq32 = emb_ti + NE * NC;              // 4096 f32
  int*    win      = (int*)(emb_sq32 + NE);         // 64*256 int
  unsigned* cnt    = (unsigned*)(win + NB * 256);   // 1
  unsigned* gbar   = cnt + 1;                       // 1
  unsigned* flags  = gbar + 1;                      // 64*16 one-shot cells

  k_fused<<<GRID, TPB, 0, stream>>>(z, emb, phi_w, phi_b,
                                    rv64, emb_sq, loss_d, emb_ti, emb_sq32,
                                    win, cnt, gbar, flags,
                                    out_zhat, out_loss, out_idx);
}